// Round 9
// baseline (179.277 us; speedup 1.0000x reference)
//
#include <hip/hip_runtime.h>

// LocalNonLocal2D v8 = v6 staging/compute, re-sharded: 8 waves x 16 channels.
//   Single variable vs v6 (73us): waves/block 4->8 (512 thr), ch/wave 32->16
//   (4 groups of 4ch), ring-2 depth-1 prefetch (v3's proven issue-before-
//   compute pattern, counted s_waitcnt vmcnt(15/0)). LDS identical 75.3KB ->
//   2 blocks/CU -> 16 waves/CU (2x v6's TLP), per-wave chain halved.
//   Halo: 10 rows x 23 float4 (odd stride), global_load_lds gather staging.
//   Cross-wave w[49] reduce via LDS atomics into wred[64][53].

namespace {

constexpr int CN = 4, CC = 128, HT = 80, WD = 80;
constexpr int KK = 7, K2 = 49, PD = 3;
constexpr int TW = 16, TH = 4;            // pixel tile (64 px, lane = pixel)
constexpr int HROW = 23;                  // halo row stride in float4 (odd)
constexpr int HENT = 10 * HROW;           // 230 float4 entries
constexpr int HCHUNK = (HENT * 4 + 63) / 64;  // 15 chunks of 64 floats
constexpr int HPADF = HCHUNK * 64;        // 960 floats per buffer
constexpr int PLANE = HT * WD;            // 6400
constexpr int GSTRIDE = 4 * PLANE;        // one 4-channel group step
constexpr int OUT_ELEMS = CN * CC * PLANE;
constexpr int NW = 8, GPW = 4;            // 8 waves x 16 ch (4 groups of 4)
constexpr int WR = 53;                    // wred row stride (odd)

__device__ __forceinline__ void make_off(int* off, int bx, int by, int lane) {
#pragma unroll
  for (int q = 0; q < HCHUNK; ++q) {
    int f = q * 64 + lane;
    int e = f >> 2;
    if (e > HENT - 1) e = HENT - 1;   // tail-pad lanes re-load last entry
    const int ch = f & 3;
    const int r  = e / HROW;
    const int cl = e - r * HROW;      // 0..22; col 22 = row pad, never read
    int gh = by * TH - PD + r;
    gh = gh < 0 ? 0 : (gh > HT - 1 ? HT - 1 : gh);
    int gw = bx * TW - PD + cl;
    gw = gw < 0 ? 0 : (gw > WD - 1 ? WD - 1 : gw);
    off[q] = ch * PLANE + gh * WD + gw;  // clamped; OOB taps zeroed later
  }
}

__device__ __forceinline__ void issue_chunks(const float* gbase, const int* off,
                                             float* lds) {
#if __has_builtin(__builtin_amdgcn_global_load_lds)
#pragma unroll
  for (int q = 0; q < HCHUNK; ++q) {
    __builtin_amdgcn_global_load_lds(
        (const __attribute__((address_space(1))) void*)(gbase + off[q]),
        (__attribute__((address_space(3))) void*)(lds + q * 64), 4, 0, 0);
  }
#else
  const int lane = (int)(threadIdx.x & 63);
#pragma unroll
  for (int q = 0; q < HCHUNK; ++q) lds[q * 64 + lane] = gbase[off[q]];
  asm volatile("s_waitcnt lgkmcnt(0)" ::: "memory");
#endif
}

#define WAIT_VM(n_lit)                                      \
  asm volatile("s_waitcnt vmcnt(" #n_lit ")" ::: "memory"); \
  __builtin_amdgcn_sched_barrier(0)

__global__ __launch_bounds__(512) void lnl2d_v8(const float* __restrict__ x,
                                                const float* __restrict__ feat,
                                                float* __restrict__ dout) {
  __shared__ float halo[NW * 2][HPADF];   // 61440 B (2 buffers per wave)
  __shared__ float wred[64][WR];          // 13568 B
  __shared__ float inv[64];               // 256 B -> 75.3 KB, 2 blocks/CU

  const int tid  = (int)threadIdx.x;
  const int wv   = tid >> 6;
  const int lane = tid & 63;
  const int tx = lane & (TW - 1), ty = lane >> 4;
  const int bx = (int)blockIdx.x, by = (int)blockIdx.y, n = (int)blockIdx.z;
  const int h = by * TH + ty, w = bx * TW + tx;

  const float* xw = x + (size_t)n * CC * PLANE + (size_t)wv * 16 * PLANE;
  const float* fw = feat + (size_t)n * CC * PLANE + (size_t)wv * 16 * PLANE;
  float* out = dout;
  float* pw  = dout + OUT_ELEMS;

  int off[HCHUNK];
  make_off(off, bx, by, lane);

  // init wred; barrier before any atomics land (vmcnt==0 here: free drain)
#pragma unroll
  for (int i = 0; i < (64 * WR + 511) / 512; ++i) {
    const int idx = i * 512 + tid;
    if (idx < 64 * WR) ((float*)wred)[idx] = 0.f;
  }
  __syncthreads();

  float* hb0 = halo[wv * 2 + 0];
  float* hb1 = halo[wv * 2 + 1];

  // ---------------- phase 1: per-wave partial correlation ------------------
  float acc[K2];
#pragma unroll
  for (int k = 0; k < K2; ++k) acc[k] = 0.f;

  auto corr = [&](const float* b) {
    const float4* h4 = (const float4*)b;
    const float4 c4 = h4[(ty + PD) * HROW + tx + PD];
#pragma unroll
    for (int di = 0; di < KK; ++di)
#pragma unroll
      for (int dj = 0; dj < KK; ++dj) {
        const float4 n4 = h4[(ty + di) * HROW + tx + dj];
        acc[di * KK + dj] += c4.x * n4.x + c4.y * n4.y + c4.z * n4.z + c4.w * n4.w;
      }
  };

  // v3-pattern ring-2: issue g+1 into the other buffer, wait(15), compute g.
  issue_chunks(xw + 0 * GSTRIDE, off, hb0);
  issue_chunks(xw + 1 * GSTRIDE, off, hb1);  WAIT_VM(15);  corr(hb0);  // g0
  issue_chunks(xw + 2 * GSTRIDE, off, hb0);  WAIT_VM(15);  corr(hb1);  // g1
  issue_chunks(xw + 3 * GSTRIDE, off, hb1);  WAIT_VM(15);  corr(hb0);  // g2
  WAIT_VM(0);                                              corr(hb1);  // g3

  // zero OOB taps (zero-padding semantics), cross-wave reduce in LDS
#pragma unroll
  for (int di = 0; di < KK; ++di)
#pragma unroll
    for (int dj = 0; dj < KK; ++dj) {
      const int hh = h + di - PD, ww = w + dj - PD;
      if ((unsigned)hh >= (unsigned)HT || (unsigned)ww >= (unsigned)WD)
        acc[di * KK + dj] = 0.f;
    }
#pragma unroll
  for (int k = 0; k < K2; ++k) atomicAdd(&wred[lane][k], acc[k]);

  __syncthreads();  // vmcnt==0 here (phase 1 drained): free barrier

  // ---- feat prologue first, normalize math under its latency --------------
  issue_chunks(fw + 0 * GSTRIDE, off, hb0);

  float wk[K2];
  float ssum = 0.f;
#pragma unroll
  for (int k = 0; k < K2; ++k) { wk[k] = wred[lane][k]; ssum += wk[k]; }
  const float invs = 1.0f / ssum;
#pragma unroll
  for (int k = 0; k < K2; ++k) wk[k] *= invs;
  if (wv == 0) inv[lane] = invs;

  // ---------------- phase 2: per-wave aggregation over feat ----------------
  float4 ov[GPW];
#pragma unroll
  for (int g = 0; g < GPW; ++g) ov[g] = make_float4(0.f, 0.f, 0.f, 0.f);

  auto agg = [&](const float* b, float4& o) {
    const float4* h4 = (const float4*)b;
#pragma unroll
    for (int di = 0; di < KK; ++di)
#pragma unroll
      for (int dj = 0; dj < KK; ++dj) {
        const float4 n4 = h4[(ty + di) * HROW + tx + dj];
        const float f = wk[di * KK + dj];
        o.x += f * n4.x; o.y += f * n4.y; o.z += f * n4.z; o.w += f * n4.w;
      }
  };

  issue_chunks(fw + 1 * GSTRIDE, off, hb1);  WAIT_VM(15);  agg(hb0, ov[0]);
  issue_chunks(fw + 2 * GSTRIDE, off, hb0);  WAIT_VM(15);  agg(hb1, ov[1]);
  issue_chunks(fw + 3 * GSTRIDE, off, hb1);  WAIT_VM(15);  agg(hb0, ov[2]);
  WAIT_VM(0);                                              agg(hb1, ov[3]);

  const size_t ob = (size_t)n * CC * PLANE + (size_t)wv * 16 * PLANE +
                    (size_t)(h * WD + w);
#pragma unroll
  for (int g = 0; g < GPW; ++g) {
    out[ob + (size_t)(4 * g + 0) * PLANE] = ov[g].x;
    out[ob + (size_t)(4 * g + 1) * PLANE] = ov[g].y;
    out[ob + (size_t)(4 * g + 2) * PLANE] = ov[g].z;
    out[ob + (size_t)(4 * g + 3) * PLANE] = ov[g].w;
  }

  __syncthreads();  // wred/inv stable for the cooperative pairwise store

  // ---- pairwise_weight (n,h,w,k): 784 contiguous floats per tile row ------
#pragma unroll
  for (int r = 0; r < TH; ++r) {
    float* seg = pw + (size_t)(n * PLANE + (by * TH + r) * WD + bx * TW) * K2;
    {
      const int idx = tid;  // 512 threads: one chunk + remainder (784 total)
      const int col = idx / K2, k = idx - col * K2;
      seg[idx] = wred[r * TW + col][k] * inv[r * TW + col];
    }
    const int idx2 = 512 + tid;
    if (idx2 < TW * K2) {
      const int col = idx2 / K2, k = idx2 - col * K2;
      seg[idx2] = wred[r * TW + col][k] * inv[r * TW + col];
    }
  }
}

}  // namespace

extern "C" void kernel_launch(void* const* d_in, const int* in_sizes, int n_in,
                              void* d_out, int out_size, void* d_ws, size_t ws_size,
                              hipStream_t stream) {
  const float* x    = (const float*)d_in[0];
  const float* feat = (const float*)d_in[1];
  float* out        = (float*)d_out;
  dim3 grid(WD / TW, HT / TH, CN);  // (5, 20, 4) = 400 blocks x 512 threads
  lnl2d_v8<<<grid, 512, 0, stream>>>(x, feat, out);
}